// Round 6
// baseline (3375.111 us; speedup 1.0000x reference)
//
#include <hip/hip_runtime.h>
#include <hip/hip_bf16.h>
#include <math.h>

// EncoderRNN on MI355X. Inputs fp32, output fp32.
// R17 = R16 + occupancy/parallelism package:
//  - k_uw: 65-block two-stage deterministic reduce (was 9 blocks, 42 us).
//  - gemm3/gemm2 + k_xgates: single-buffered 64 KB LDS, __launch_bounds__(256,2)
//    -> 2 blocks/CU co-residency (cross-block stall hiding, m114 mechanism).
//  - k_xgates grid 512 (K-halved, kh in {0,1}), atomicAdd into pre-zeroed Gx
//    (exactly 2 contributions/element; Gx memset after k_efin consumes Ep).
//  - k_step grid 512 = 16 jobs x 32 ct: j0-7 w1hh 3-prod K-eighths -> P0 (8
//    contribs), j8-11 w2ih 2-prod K-quarters -> P2, j12-15 w2hh -> P3.
//    Contributors for one element share an XCD (bid%8 = ct%8) -> L2 atomics.
//  - k_elem: P1 removed (lstm1 = Gx + P0 + b1); consume-and-clear unchanged.
// Embed path unchanged from R16 (k_embed 128KB dbuf, k_efin).

typedef __attribute__((ext_vector_type(8))) short short8;
typedef __attribute__((ext_vector_type(4))) short short4v;
typedef __attribute__((ext_vector_type(4))) float f32x4;
typedef __hip_bfloat16 bf16;

__device__ __forceinline__ float sigm(float x) { return 1.0f / (1.0f + expf(-x)); }
__device__ __forceinline__ short bfbits(float x) {
  bf16 h = __float2bfloat16(x);
  return __builtin_bit_cast(short, h);
}
// two f32x4 (regs) -> bf16 hi + residual lo
__device__ __forceinline__ void cvtfp(const f32x4 a, const f32x4 b,
                                      short8& hi, short8& lo)
{
#pragma unroll
  for (int j = 0; j < 8; ++j) {
    float x = (j < 4) ? a[j] : b[j - 4];
    bf16 h = __float2bfloat16(x);
    hi[j] = __builtin_bit_cast(short, h);
    lo[j] = bfbits(x - __bfloat162float(h));
  }
}

// LDS geometry: tile = 128x64 bf16 = 8192 shorts. Single buffer = 4 tiles =
// 32768 shorts (64 KB) -> 2 blocks/CU. XOR-swizzled rows.
#define TILE 8192
#define BUF  32768

// staging indices (row/seg/swizzled-offset) for 256 threads x 4 iters
#define STAGE_IDX                                              \
  int srow[4], sseg[4], ssw[4];                                \
  _Pragma("unroll")                                            \
  for (int i = 0; i < 4; ++i) {                                \
    int linear = i * 256 + threadIdx.x;                        \
    srow[i] = linear >> 3;                                     \
    sseg[i] = linear & 7;                                      \
    ssw[i]  = (sseg[i] ^ (srow[i] & 7)) * 8;                   \
  }

// MFMA fragment constants
#define FRAG_IDX                                               \
  const int lane = threadIdx.x & 63, wave = threadIdx.x >> 6;  \
  const int wr = (wave & 1) * 64, wc = (wave >> 1) * 64;       \
  const int m = lane & 15, kg = lane >> 4;

// ---------------------------------------------------------------------------
// gemm3: acc += Ah@Bh^T + Al@Bh^T + Ah@Bl^T over nChunks K-chunks of 64.
// Single-buffer 64 KB: [compute c | sync | STORE(c+1) LOAD(c+2) | sync].
// Optional A-row mask: keep iff (smk[row]>0.5)==(pol!=0).
// ---------------------------------------------------------------------------
__device__ __forceinline__ void gemm3(
    const bf16* __restrict__ Ah, const bf16* __restrict__ Al,
    const bf16* __restrict__ Bh, const bf16* __restrict__ Bl,
    int nChunks, const float* __restrict__ smk, int pol,
    short* ls, f32x4 acc[4][4])
{
  STAGE_IDX
  FRAG_IDX
  bool keep[4];
#pragma unroll
  for (int i = 0; i < 4; ++i)
    keep[i] = (smk == nullptr) || ((smk[srow[i]] > 0.5f) == (pol != 0));

  const short8 zz = {};
  short8 rah[4], ral[4], rbh[4], rbl[4];

  auto LOAD = [&](int c) {
#pragma unroll
    for (int i = 0; i < 4; ++i) {
      size_t o = (size_t)srow[i] * 1024 + c * 64 + sseg[i] * 8;
      rah[i] = keep[i] ? *(const short8*)(Ah + o) : zz;
      ral[i] = keep[i] ? *(const short8*)(Al + o) : zz;
      rbh[i] = *(const short8*)(Bh + o);
      rbl[i] = *(const short8*)(Bl + o);
    }
  };
  auto STORE = [&]() {
#pragma unroll
    for (int i = 0; i < 4; ++i) {
      int o = srow[i] * 64 + ssw[i];
      *(short8*)(ls + o)            = rah[i];
      *(short8*)(ls + TILE + o)     = ral[i];
      *(short8*)(ls + 2 * TILE + o) = rbh[i];
      *(short8*)(ls + 3 * TILE + o) = rbl[i];
    }
  };

  LOAD(0); STORE();
  if (nChunks > 1) LOAD(1);
  __syncthreads();

  for (int c = 0; c < nChunks; ++c) {
#pragma unroll
    for (int ks = 0; ks < 2; ++ks) {
      short8 afh[4], afl[4], bfh[4], bfl[4];
      int asw[4], bsw[4];
#pragma unroll
      for (int f = 0; f < 4; ++f) {
        int ar = wr + f * 16 + m;
        asw[f] = ar * 64 + (((ks * 4 + kg) ^ (ar & 7)) * 8);
        int br = wc + f * 16 + m;
        bsw[f] = br * 64 + (((ks * 4 + kg) ^ (br & 7)) * 8);
        afh[f] = *(const short8*)(ls + asw[f]);
        bfh[f] = *(const short8*)(ls + 2 * TILE + bsw[f]);
      }
#pragma unroll
      for (int fr = 0; fr < 4; ++fr)
#pragma unroll
        for (int fc = 0; fc < 4; ++fc)
          acc[fr][fc] = __builtin_amdgcn_mfma_f32_16x16x32_bf16(afh[fr], bfh[fc], acc[fr][fc], 0, 0, 0);
#pragma unroll
      for (int f = 0; f < 4; ++f)
        afl[f] = *(const short8*)(ls + TILE + asw[f]);
#pragma unroll
      for (int fr = 0; fr < 4; ++fr)
#pragma unroll
        for (int fc = 0; fc < 4; ++fc)
          acc[fr][fc] = __builtin_amdgcn_mfma_f32_16x16x32_bf16(afl[fr], bfh[fc], acc[fr][fc], 0, 0, 0);
#pragma unroll
      for (int f = 0; f < 4; ++f)
        bfl[f] = *(const short8*)(ls + 3 * TILE + bsw[f]);
#pragma unroll
      for (int fr = 0; fr < 4; ++fr)
#pragma unroll
        for (int fc = 0; fc < 4; ++fc)
          acc[fr][fc] = __builtin_amdgcn_mfma_f32_16x16x32_bf16(afh[fr], bfl[fc], acc[fr][fc], 0, 0, 0);
    }
    if (c + 1 < nChunks) {
      __syncthreads();
      STORE();
      if (c + 2 < nChunks) LOAD(c + 2);
      __syncthreads();
    }
  }
}

// ---------------------------------------------------------------------------
// gemm2: acc += Ah@B^T + Al@B^T (B hi-only). Single-buffer 64 KB.
// ---------------------------------------------------------------------------
__device__ __forceinline__ void gemm2(
    const bf16* __restrict__ Ah, const bf16* __restrict__ Al,
    const bf16* __restrict__ B,
    int nChunks, const float* __restrict__ smk, int pol,
    short* ls, f32x4 acc[4][4])
{
  STAGE_IDX
  FRAG_IDX
  bool keep[4];
#pragma unroll
  for (int i = 0; i < 4; ++i)
    keep[i] = (smk == nullptr) || ((smk[srow[i]] > 0.5f) == (pol != 0));

  const short8 zz = {};
  short8 rah[4], ral[4], rb[4];

  auto LOAD = [&](int c) {
#pragma unroll
    for (int i = 0; i < 4; ++i) {
      size_t o = (size_t)srow[i] * 1024 + c * 64 + sseg[i] * 8;
      rah[i] = keep[i] ? *(const short8*)(Ah + o) : zz;
      ral[i] = keep[i] ? *(const short8*)(Al + o) : zz;
      rb[i]  = *(const short8*)(B + o);
    }
  };
  auto STORE = [&]() {
#pragma unroll
    for (int i = 0; i < 4; ++i) {
      int o = srow[i] * 64 + ssw[i];
      *(short8*)(ls + o)            = rah[i];
      *(short8*)(ls + TILE + o)     = ral[i];
      *(short8*)(ls + 2 * TILE + o) = rb[i];
    }
  };

  LOAD(0); STORE();
  if (nChunks > 1) LOAD(1);
  __syncthreads();

  for (int c = 0; c < nChunks; ++c) {
#pragma unroll
    for (int ks = 0; ks < 2; ++ks) {
      short8 afh[4], afl[4], bf[4];
      int asw[4], bsw[4];
#pragma unroll
      for (int f = 0; f < 4; ++f) {
        int ar = wr + f * 16 + m;
        asw[f] = ar * 64 + (((ks * 4 + kg) ^ (ar & 7)) * 8);
        int br = wc + f * 16 + m;
        bsw[f] = br * 64 + (((ks * 4 + kg) ^ (br & 7)) * 8);
        afh[f] = *(const short8*)(ls + asw[f]);
        bf[f]  = *(const short8*)(ls + 2 * TILE + bsw[f]);
      }
#pragma unroll
      for (int fr = 0; fr < 4; ++fr)
#pragma unroll
        for (int fc = 0; fc < 4; ++fc)
          acc[fr][fc] = __builtin_amdgcn_mfma_f32_16x16x32_bf16(afh[fr], bf[fc], acc[fr][fc], 0, 0, 0);
#pragma unroll
      for (int f = 0; f < 4; ++f)
        afl[f] = *(const short8*)(ls + TILE + asw[f]);
#pragma unroll
      for (int fr = 0; fr < 4; ++fr)
#pragma unroll
        for (int fc = 0; fc < 4; ++fc)
          acc[fr][fc] = __builtin_amdgcn_mfma_f32_16x16x32_bf16(afl[fr], bf[fc], acc[fr][fc], 0, 0, 0);
    }
    if (c + 1 < nChunks) {
      __syncthreads();
      STORE();
      if (c + 2 < nChunks) LOAD(c + 2);
      __syncthreads();
    }
  }
}

// C/D frag layout (m89/m91-verified): col = lane&15, row = (lane>>4)*4 + reg.
template <typename F>
__device__ __forceinline__ void epilogue(const f32x4 acc[4][4], F&& body)
{
  FRAG_IDX
#pragma unroll
  for (int fr = 0; fr < 4; ++fr)
#pragma unroll
    for (int fc = 0; fc < 4; ++fc)
#pragma unroll
      for (int r = 0; r < 4; ++r)
        body(wr + fr * 16 + kg * 4 + r, wc + fc * 16 + m, acc[fr][fc][r]);
}

// ---------------------------------------------------------------------------
__global__ void k_diag(float* __restrict__ out, float val)
{
  if (threadIdx.x == 0 && blockIdx.x == 0) out[0] = val;
}

// u[h]=sum_m vs[m]*Wsi[m,h]; w[h]=sum_m vs[m]*Wsh[m,h]; cbd=b_bd.vs (fp64).
// Grid 65: blk<32 -> u (32 h-cols each), blk<64 -> wv, blk 64 -> cbd.
// Two-stage deterministic reduce: 8 m-groups x 32 h per block, LDS combine.
__global__ void k_uw(const float* __restrict__ Wsi, const float* __restrict__ Wsh,
                     const float* __restrict__ bbd, const float* __restrict__ vs,
                     double* __restrict__ u, double* __restrict__ wv,
                     double* __restrict__ cbdp)
{
  __shared__ double red[256];
  const int blk = blockIdx.x;
  const int tid = threadIdx.x;
  if (blk < 64) {
    const float* W = (blk < 32) ? Wsi : Wsh;
    double* out = (blk < 32) ? u : wv;
    const int hbase = (blk & 31) * 32;
    const int h = hbase + (tid & 31);
    const int g = tid >> 5;   // 0..7 m-groups of 64
    double a = 0.0;
    for (int mm = g * 64; mm < g * 64 + 64; ++mm)
      a += (double)vs[mm] * (double)W[mm * 1024 + h];
    red[tid] = a;
    __syncthreads();
    if (tid < 32) {
      double sum = 0.0;
#pragma unroll
      for (int g2 = 0; g2 < 8; ++g2) sum += red[g2 * 32 + tid];
      out[hbase + tid] = sum;
    }
  } else if (tid < 64) {
    double a = 0.0;
    for (int mm = tid; mm < 512; mm += 64)
      a += (double)vs[mm] * (double)bbd[mm];
#pragma unroll
    for (int o = 32; o > 0; o >>= 1) a += __shfl_down(a, o, 64);
    if (tid == 0) cbdp[0] = a;
  }
}

// weight split: m0 = w1hh -> hi+lo; m1 = w2ih -> hi; m2 = w2hh -> hi
__global__ void k_wsplit(const float* __restrict__ w1hh, const float* __restrict__ w2ih,
                         const float* __restrict__ w2hh,
                         bf16* __restrict__ o1hh_h, bf16* __restrict__ o1hh_l,
                         bf16* __restrict__ o2ih_h, bf16* __restrict__ o2hh_h)
{
  const int m = blockIdx.x >> 12;
  const size_t i4 = (size_t)(blockIdx.x & 4095) * 256 + threadIdx.x;
  const float* src = (m == 0) ? w1hh : (m == 1) ? w2ih : w2hh;
  bf16* dh = (m == 0) ? o1hh_h : (m == 1) ? o2ih_h : o2hh_h;
  bf16* dl = (m == 0) ? o1hh_l : nullptr;
  f32x4 v = *(const f32x4*)(src + i4 * 4);
  short4v hv, lv;
#pragma unroll
  for (int j = 0; j < 4; ++j) {
    float x = v[j];
    bf16 h = __float2bfloat16(x);
    hv[j] = __builtin_bit_cast(short, h);
    lv[j] = bfbits(x - __bfloat162float(h));
  }
  *(short4v*)((short*)dh + i4 * 4) = hv;
  if (dl) *(short4v*)((short*)dl + i4 * 4) = lv;
}

// ---------------------------------------------------------------------------
// embed (K-split x4, 128 KB dbuf — unchanged from R16): Ep[kh] = video(Krange)
// @ Wemb(Krange)^T, fused 3-product split, fp32 cvt at LDS-write.
// Block = (tl 0..7, ct 0..7, kh 0..3); 8 chunks.
// ---------------------------------------------------------------------------
__global__ __launch_bounds__(256, 1) void k_embed(
    const float* __restrict__ video, const float* __restrict__ Wemb,
    float* __restrict__ Ep, int tbase)
{
  __shared__ __align__(16) short ls[65536];
  const int tl = blockIdx.x >> 5;
  const int ct = (blockIdx.x >> 2) & 7;
  const int kh = blockIdx.x & 3;

  STAGE_IDX
  FRAG_IDX
  const float* arow[4];
  const float* brow[4];
#pragma unroll
  for (int i = 0; i < 4; ++i) {
    arow[i] = video + (size_t)(srow[i] * 64 + tbase + tl) * 2048 + kh * 512 + sseg[i] * 8;
    brow[i] = Wemb + (size_t)(ct * 128 + srow[i]) * 2048 + kh * 512 + sseg[i] * 8;
  }

  f32x4 fa[4][2], fb[4][2];
  auto LOAD = [&](int c) {
#pragma unroll
    for (int i = 0; i < 4; ++i) {
      fa[i][0] = *(const f32x4*)(arow[i] + c * 64);
      fa[i][1] = *(const f32x4*)(arow[i] + c * 64 + 4);
      fb[i][0] = *(const f32x4*)(brow[i] + c * 64);
      fb[i][1] = *(const f32x4*)(brow[i] + c * 64 + 4);
    }
  };
  auto STORE = [&](int buf) {
    short* p = ls + buf * BUF;
#pragma unroll
    for (int i = 0; i < 4; ++i) {
      short8 hi, lo;
      int o = srow[i] * 64 + ssw[i];
      cvtfp(fa[i][0], fa[i][1], hi, lo);
      *(short8*)(p + o)        = hi;
      *(short8*)(p + TILE + o) = lo;
      cvtfp(fb[i][0], fb[i][1], hi, lo);
      *(short8*)(p + 2 * TILE + o) = hi;
      *(short8*)(p + 3 * TILE + o) = lo;
    }
  };

  f32x4 acc[4][4] = {};
  LOAD(0); STORE(0);
  LOAD(1);
  __syncthreads();

  for (int c = 0; c < 8; ++c) {
    if (c + 1 < 8) STORE((c + 1) & 1);
    if (c + 2 < 8) LOAD(c + 2);
    const short* la = ls + (c & 1) * BUF;
#pragma unroll
    for (int ks = 0; ks < 2; ++ks) {
      short8 afh[4], afl[4], bfh[4], bfl[4];
      int asw[4], bsw[4];
#pragma unroll
      for (int f = 0; f < 4; ++f) {
        int ar = wr + f * 16 + m;
        asw[f] = ar * 64 + (((ks * 4 + kg) ^ (ar & 7)) * 8);
        int br = wc + f * 16 + m;
        bsw[f] = br * 64 + (((ks * 4 + kg) ^ (br & 7)) * 8);
        afh[f] = *(const short8*)(la + asw[f]);
        bfh[f] = *(const short8*)(la + 2 * TILE + bsw[f]);
      }
#pragma unroll
      for (int fr = 0; fr < 4; ++fr)
#pragma unroll
        for (int fc = 0; fc < 4; ++fc)
          acc[fr][fc] = __builtin_amdgcn_mfma_f32_16x16x32_bf16(afh[fr], bfh[fc], acc[fr][fc], 0, 0, 0);
#pragma unroll
      for (int f = 0; f < 4; ++f)
        afl[f] = *(const short8*)(la + TILE + asw[f]);
#pragma unroll
      for (int fr = 0; fr < 4; ++fr)
#pragma unroll
        for (int fc = 0; fc < 4; ++fc)
          acc[fr][fc] = __builtin_amdgcn_mfma_f32_16x16x32_bf16(afl[fr], bfh[fc], acc[fr][fc], 0, 0, 0);
#pragma unroll
      for (int f = 0; f < 4; ++f)
        bfl[f] = *(const short8*)(la + 3 * TILE + bsw[f]);
#pragma unroll
      for (int fr = 0; fr < 4; ++fr)
#pragma unroll
        for (int fc = 0; fc < 4; ++fc)
          acc[fr][fc] = __builtin_amdgcn_mfma_f32_16x16x32_bf16(afh[fr], bfl[fc], acc[fr][fc], 0, 0, 0);
    }
    if (c + 1 < 8) __syncthreads();
  }

  epilogue(acc, [&](int lrow, int lcol, float aval) {
    Ep[(size_t)kh * 1048576 + (size_t)(tl * 128 + lrow) * 1024 + ct * 128 + lcol] = aval;
  });
}

// sum 4 K-partials + bias, relu, split -> v ring (slot-linear)
__global__ void k_efin(const float* __restrict__ Ep, const float* __restrict__ bemb,
                       bf16* __restrict__ vhi, bf16* __restrict__ vlo)
{
  const size_t e = ((size_t)blockIdx.x * 256 + threadIdx.x) * 4;
  f32x4 a0 = *(const f32x4*)(Ep + e);
  f32x4 a1 = *(const f32x4*)(Ep + 1048576 + e);
  f32x4 a2 = *(const f32x4*)(Ep + 2097152 + e);
  f32x4 a3 = *(const f32x4*)(Ep + 3145728 + e);
  f32x4 bb = *(const f32x4*)(bemb + (e & 1023));
  short4v hv, lv;
#pragma unroll
  for (int j = 0; j < 4; ++j) {
    float x = a0[j] + a1[j] + a2[j] + a3[j] + bb[j];
    x = fmaxf(x, 0.0f);
    bf16 h = __float2bfloat16(x);
    hv[j] = __builtin_bit_cast(short, h);
    lv[j] = bfbits(x - __bfloat162float(h));
  }
  *(short4v*)((short*)vhi + e) = hv;
  *(short4v*)((short*)vlo + e) = lv;
}

// ---------------------------------------------------------------------------
// xgates: Gx[rt] += vh@W1ih_h + vl@W1ih_h + vh@W1ih_l over a K-half.
// Grid 512: x=bid&7 (XCD), s=bid>>3: ct = x*4+(s&3), rt = (s>>2)&7, kh = s>>5.
// Single-buffer 64 KB, 2 blocks/CU; 8 chunks; atomicAdd (2 contribs/element,
// Gx pre-zeroed). Blocks sharing a W1ih ct-slice land on one XCD.
// ---------------------------------------------------------------------------
__global__ __launch_bounds__(256, 2) void k_xgates(
    const bf16* __restrict__ vhi, const bf16* __restrict__ vlo,
    const float* __restrict__ Wih1, float* __restrict__ Gx)
{
  __shared__ __align__(16) short ls[32768];
  const int x  = blockIdx.x & 7;
  const int s  = blockIdx.x >> 3;
  const int ct = x * 4 + (s & 3);
  const int rt = (s >> 2) & 7;
  const int kh = s >> 5;   // 0..1 K-half

  STAGE_IDX
  FRAG_IDX
  const bf16* arh[4];
  const bf16* arl[4];
  const float* brow[4];
#pragma unroll
  for (int i = 0; i < 4; ++i) {
    size_t ro = (size_t)srow[i] * 1024 + kh * 512 + sseg[i] * 8;
    arh[i] = vhi + (size_t)rt * 131072 + ro;
    arl[i] = vlo + (size_t)rt * 131072 + ro;
    brow[i] = Wih1 + (size_t)(ct * 128 + srow[i]) * 1024 + kh * 512 + sseg[i] * 8;
  }

  short8 rah[4], ral[4];
  f32x4 fb[4][2];
  auto LOAD = [&](int c) {
#pragma unroll
    for (int i = 0; i < 4; ++i) {
      rah[i] = *(const short8*)(arh[i] + c * 64);
      ral[i] = *(const short8*)(arl[i] + c * 64);
      fb[i][0] = *(const f32x4*)(brow[i] + c * 64);
      fb[i][1] = *(const f32x4*)(brow[i] + c * 64 + 4);
    }
  };
  auto STORE = [&]() {
#pragma unroll
    for (int i = 0; i < 4; ++i) {
      int o = srow[i] * 64 + ssw[i];
      *(short8*)(ls + o)        = rah[i];
      *(short8*)(ls + TILE + o) = ral[i];
      short8 hi, lo;
      cvtfp(fb[i][0], fb[i][1], hi, lo);
      *(short8*)(ls + 2 * TILE + o) = hi;
      *(short8*)(ls + 3 * TILE + o) = lo;
    }
  };

  f32x4 acc[4][4] = {};
  LOAD(0); STORE();
  LOAD(1);
  __syncthreads();

  for (int c = 0; c < 8; ++c) {
#pragma unroll
    for (int ks = 0; ks < 2; ++ks) {
      short8 afh[4], afl[4], bfh[4], bfl[4];
      int asw[4], bsw[4];
#pragma unroll
      for (int f = 0; f < 4; ++f) {
        int ar = wr + f * 16 + m;
        asw[f] = ar * 64 + (((ks * 4 + kg) ^ (ar & 7)) * 8);
        int br = wc + f * 16 + m;
        bsw[f] = br * 64 + (((ks * 4 + kg) ^ (br & 7)) * 8);
        afh[f] = *(const short8*)(ls + asw[f]);
        bfh[f] = *(const short8*)(ls + 2 * TILE + bsw[f]);
      }
#pragma unroll
      for (int fr = 0; fr < 4; ++fr)
#pragma unroll
        for (int fc = 0; fc < 4; ++fc)
          acc[fr][fc] = __builtin_amdgcn_mfma_f32_16x16x32_bf16(afh[fr], bfh[fc], acc[fr][fc], 0, 0, 0);
#pragma unroll
      for (int f = 0; f < 4; ++f)
        afl[f] = *(const short8*)(ls + TILE + asw[f]);
#pragma unroll
      for (int fr = 0; fr < 4; ++fr)
#pragma unroll
        for (int fc = 0; fc < 4; ++fc)
          acc[fr][fc] = __builtin_amdgcn_mfma_f32_16x16x32_bf16(afl[fr], bfh[fc], acc[fr][fc], 0, 0, 0);
#pragma unroll
      for (int f = 0; f < 4; ++f)
        bfl[f] = *(const short8*)(ls + 3 * TILE + bsw[f]);
#pragma unroll
      for (int fr = 0; fr < 4; ++fr)
#pragma unroll
        for (int fc = 0; fc < 4; ++fc)
          acc[fr][fc] = __builtin_amdgcn_mfma_f32_16x16x32_bf16(afh[fr], bfl[fc], acc[fr][fc], 0, 0, 0);
    }
    if (c + 1 < 8) {
      __syncthreads();
      STORE();
      if (c + 2 < 8) LOAD(c + 2);
      __syncthreads();
    }
  }

  epilogue(acc, [&](int lrow, int lcol, float aval) {
    atomicAdd(&Gx[(size_t)rt * 524288 + (size_t)lrow * 4096 + ct * 128 + lcol], aval);
  });
}

// ---------------------------------------------------------------------------
// G_k (h-side): grid 512, job = bid>>5 (0..15), ct = bid&31.
//  j0..7:   w1hh 3-prod K-eighths (2 chunks) -> atomic P0 (8 contribs)
//  j8..11:  w2ih 2-prod K-quarters (4 chunks) -> atomic P2 (4 contribs)
//  j12..15: w2hh 2-prod K-quarters -> atomic P3 (4 contribs)
// Contributors for one element share an XCD (bid%8 = ct%8). Partials zeroed
// by the consumer (k_elem) / initial memset.
// ---------------------------------------------------------------------------
__global__ __launch_bounds__(256, 2) void k_step(
    const bf16* __restrict__ h1nh, const bf16* __restrict__ h1nl,
    const bf16* __restrict__ h2h, const bf16* __restrict__ h2l,
    const bf16* __restrict__ w1hh_h, const bf16* __restrict__ w1hh_l,
    const bf16* __restrict__ w2ih_h, const bf16* __restrict__ w2hh_h,
    const float* __restrict__ sm, float* __restrict__ R, int k)
{
  __shared__ __align__(16) short ls[32768];
  const int job = blockIdx.x >> 5;
  const int ct  = blockIdx.x & 31;
  if (k == 64 && job < 8) return;   // E_64 only consumes lstm2 partials

  f32x4 acc[4][4] = {};
  const size_t cto = (size_t)ct * 131072;
  int idx;
  if (job < 8) {
    const size_t ko = (size_t)job * 128;
    gemm3(h1nh + ko, h1nl + ko, w1hh_h + cto + ko, w1hh_l + cto + ko,
          2, sm, 0, ls, acc);
    idx = 0;
  } else if (job < 12) {
    const size_t ko = (size_t)(job - 8) * 256;
    gemm2(h1nh + ko, h1nl + ko, w2ih_h + cto + ko, 4, sm, 1, ls, acc);
    idx = 2;
  } else {
    const size_t ko = (size_t)(job - 12) * 256;
    gemm2(h2h + ko, h2l + ko, w2hh_h + cto + ko, 4, nullptr, 0, ls, acc);
    idx = 3;
  }

  float* Rout = R + (size_t)idx * 524288;
  epilogue(acc, [&](int lrow, int lcol, float aval) {
    atomicAdd(&Rout[(size_t)lrow * 4096 + ct * 128 + lcol], aval);
  });
}

// ---------------------------------------------------------------------------
// E_k: grid 128 (b = blockIdx), 512 threads, 2 j each.
// Inline zx (fp64 v.u); lstm1 gates = Gx[k&7] + P0 (k>0) + b1;
// lstm2 gates = P2 + P3. Consumed P elements are zeroed (atomic invariant).
// ---------------------------------------------------------------------------
__global__ void k_elem(float* __restrict__ R, const float* __restrict__ Gx,
                       const bf16* __restrict__ vhi, const bf16* __restrict__ vlo,
                       const double* __restrict__ uvec, const double* __restrict__ cbdp,
                       float* __restrict__ craw,
                       bf16* __restrict__ h1nh, bf16* __restrict__ h1nl,
                       float* __restrict__ sm,
                       float* __restrict__ c2, bf16* __restrict__ h2h, bf16* __restrict__ h2l,
                       float* __restrict__ rdm, const double* __restrict__ wv,
                       const float* __restrict__ b1, float* __restrict__ dout, int k)
{
  __shared__ double red[8];
  const int tid = threadIdx.x;
  const int b   = blockIdx.x;
  const size_t broff = (size_t)b * 4096;
  float* P0 = R + broff;
  float* P2 = P0 + 2 * 524288;
  float* P3 = P0 + 3 * 524288;
  const float* GX = Gx + (size_t)(k & 7) * 524288 + broff;

  if (k < 64) {  // boundary gate + lstm1 step k
    const bf16* vhr = vhi + (size_t)(k & 7) * 131072 + (size_t)b * 1024;
    const bf16* vlr = vlo + (size_t)(k & 7) * 131072 + (size_t)b * 1024;
    double za = 0.0;
#pragma unroll
    for (int ji = 0; ji < 2; ++ji) {
      int j = tid + ji * 512;
      za += (double)(__bfloat162float(vhr[j]) + __bfloat162float(vlr[j])) * uvec[j];
    }
#pragma unroll
    for (int o = 32; o > 0; o >>= 1) za += __shfl_down(za, o, 64);
    if ((tid & 63) == 0) red[tid >> 6] = za;
    __syncthreads();
    float zpre = (float)(red[0] + red[1] + red[2] + red[3] +
                         red[4] + red[5] + red[6] + red[7] + cbdp[0]);
    if (k > 0) zpre += rdm[(k - 1) * 128 + b];
    float s  = (sigm(zpre) > 0.5f) ? 1.0f : 0.0f;   // round(): 0.5 -> 0
    float om = 1.0f - s;
    __syncthreads();   // red about to be reused

    double rd = 0.0;
#pragma unroll
    for (int ji = 0; ji < 2; ++ji) {
      int j = tid + ji * 512;
      float gi = GX[j]        + b1[j];
      float gf = GX[1024 + j] + b1[1024 + j];
      float gg = GX[2048 + j] + b1[2048 + j];
      float go = GX[3072 + j] + b1[3072 + j];
      if (k > 0) {
        gi += P0[j];
        gf += P0[1024 + j];
        gg += P0[2048 + j];
        go += P0[3072 + j];
        // consume-and-clear for next step's atomic accumulation
        P0[j] = 0.0f; P0[1024 + j] = 0.0f; P0[2048 + j] = 0.0f; P0[3072 + j] = 0.0f;
      }
      float cn = sigm(gf) * craw[b * 1024 + j] + sigm(gi) * tanhf(gg);
      float hn = sigm(go) * tanhf(cn);
      craw[b * 1024 + j] = om * cn;
      bf16 hh = __float2bfloat16(hn);
      h1nh[b * 1024 + j] = hh;
      h1nl[b * 1024 + j] = __float2bfloat16(hn - __bfloat162float(hh));
      rd += (double)hn * wv[j];
    }
#pragma unroll
    for (int o = 32; o > 0; o >>= 1) rd += __shfl_down(rd, o, 64);
    if ((tid & 63) == 0) red[tid >> 6] = rd;
    __syncthreads();
    if (tid == 0) {
      rdm[k * 128 + b] = om * (float)(red[0] + red[1] + red[2] + red[3] +
                                      red[4] + red[5] + red[6] + red[7]);
      sm[b] = s;
    }
  }

  if (k >= 1) {  // lstm2 step k-1 (x pre-masked by s_{k-1} in k_step; bias-free)
#pragma unroll
    for (int ji = 0; ji < 2; ++ji) {
      int j = tid + ji * 512;
      float gi = P2[j]        + P3[j];
      float gf = P2[1024 + j] + P3[1024 + j];
      float gg = P2[2048 + j] + P3[2048 + j];
      float go = P2[3072 + j] + P3[3072 + j];
      // consume-and-clear for next step's atomic accumulation
      P2[j] = 0.0f; P2[1024 + j] = 0.0f; P2[2048 + j] = 0.0f; P2[3072 + j] = 0.0f;
      P3[j] = 0.0f; P3[1024 + j] = 0.0f; P3[2048 + j] = 0.0f; P3[3072 + j] = 0.0f;
      float cn = sigm(gf) * c2[b * 1024 + j] + sigm(gi) * tanhf(gg);
      float hn = sigm(go) * tanhf(cn);
      c2[b * 1024 + j] = cn;
      bf16 hh = __float2bfloat16(hn);
      h2h[b * 1024 + j] = hh;
      h2l[b * 1024 + j] = __float2bfloat16(hn - __bfloat162float(hh));
      if (k == 64) dout[b * 1024 + j] = hn;
    }
  }
}

// ---------------------------------------------------------------------------
extern "C" void kernel_launch(void* const* d_in, const int* in_sizes, int n_in,
                              void* d_out, int out_size, void* d_ws, size_t ws_size,
                              hipStream_t stream) {
  const float* video = (const float*)d_in[0];
  const float* Wemb  = (const float*)d_in[1];
  const float* bemb  = (const float*)d_in[2];
  const float* Wih1  = (const float*)d_in[3];
  const float* Whh1  = (const float*)d_in[4];
  const float* b1    = (const float*)d_in[5];
  const float* Wsi   = (const float*)d_in[6];
  const float* Wsh   = (const float*)d_in[7];
  const float* bbd   = (const float*)d_in[8];
  const float* vs    = (const float*)d_in[9];
  const float* Wih2  = (const float*)d_in[10];
  const float* Whh2  = (const float*)d_in[11];
  float* dout = (float*)d_out;

  static const int exp_sizes[12] = {
    128 * 64 * 2048, 1024 * 2048, 1024, 4096 * 1024, 4096 * 1024, 4096,
    512 * 1024, 512 * 1024, 512, 512, 4096 * 1024, 4096 * 1024 };
  int bad = -1;
  if (n_in != 12) bad = 99;
  else if (out_size != 131072) bad = 98;
  else
    for (int i = 0; i < 12; ++i)
      if (in_sizes[i] != exp_sizes[i]) { bad = i; break; }
  if (bad >= 0) {
    k_diag<<<1, 64, 0, stream>>>(dout, 10000.0f + (float)bad);
    return;
  }

  char* ws = (char*)d_ws;
  size_t off = 0;
  auto alloc = [&](size_t bytes) {
    char* p = ws + off;
    off += (bytes + 255) & ~(size_t)255;
    return p;
  };
  // zero region (state), memset each launch
  bf16*  h1nh = (bf16*)alloc(262144);
  bf16*  h1nl = (bf16*)alloc(262144);
  bf16*  h2h  = (bf16*)alloc(262144);
  bf16*  h2l  = (bf16*)alloc(262144);
  float* c2   = (float*)alloc(524288);
  float* craw = (float*)alloc(524288);
  float* sm   = (float*)alloc(512);
  const size_t zeroBytes = off;
  // rest (written before read every launch)
  double* u    = (double*)alloc(8192);
  double* wvv  = (double*)alloc(8192);
  double* cbdp = (double*)alloc(256);
  float* rdm   = (float*)alloc(64 * 128 * 4);
  bf16* w1hh_h = (bf16*)alloc(8388608);
  bf16* w1hh_l = (bf16*)alloc(8388608);
  bf16* w2ih_h = (bf16*)alloc(8388608);
  bf16* w2hh_h = (bf16*)alloc(8388608);
  float* R     = (float*)alloc(4 * 2097152);            // partials (P1 unused)
  float* Gxf   = (float*)alloc(8 * 2097152);            // Gx ring / embed Ep alias
  bf16* vhi    = (bf16*)alloc(8 * 131072 * 2);          // v ring, 8 slots
  bf16* vlo    = (bf16*)alloc(8 * 131072 * 2);

  if (ws_size < off) {
    k_diag<<<1, 64, 0, stream>>>(dout, 100.0f + (float)(ws_size >> 20));
    return;
  }

  (void)hipMemsetAsync(d_ws, 0, zeroBytes, stream);
  (void)hipMemsetAsync(R, 0, 4 * 2097152, stream);      // atomic accumulators
  k_uw<<<65, 256, 0, stream>>>(Wsi, Wsh, bbd, vs, u, wvv, cbdp);
  k_wsplit<<<12288, 256, 0, stream>>>(Whh1, Wih2, Whh2,
                                      w1hh_h, w1hh_l, w2ih_h, w2hh_h);

  for (int k = 0; k <= 64; ++k) {
    if (k < 64 && (k & 7) == 0) {
      k_embed<<<256, 256, 0, stream>>>(video, Wemb, Gxf, k);          // Ep alias
      k_efin<<<1024, 256, 0, stream>>>(Gxf, bemb, vhi, vlo);
      (void)hipMemsetAsync(Gxf, 0, 8 * 2097152, stream);              // Gx accum
      k_xgates<<<512, 256, 0, stream>>>(vhi, vlo, Wih1, Gxf);         // += Gx
    }
    if (k > 0)
      k_step<<<512, 256, 0, stream>>>(h1nh, h1nl, h2h, h2l,
                                      w1hh_h, w1hh_l, w2ih_h, w2hh_h, sm, R, k);
    k_elem<<<128, 512, 0, stream>>>(R, Gxf, vhi, vlo, u, cbdp, craw,
                                    h1nh, h1nl, sm, c2, h2h, h2l,
                                    rdm, wvv, b1, dout, k);
  }
}